// Round 5
// baseline (226.019 us; speedup 1.0000x reference)
//
#include <hip/hip_runtime.h>

// MultiheadAttentionWithBias: B=2, L=2048, D=1024, H=16, HD=64
// cvt_all -> QKV GEMM (V^T fused epilogue) -> flash attn (dbuf LDS K/V,
// counted vmcnt, XCD swizzle, per-iter rescale) -> out GEMM.
// R5: defer-rescale REMOVED (bisect vs R4 failure); rest of R4 kept.

typedef __attribute__((ext_vector_type(8))) short bf16x8;
typedef __attribute__((ext_vector_type(4))) float f32x4;
typedef __attribute__((ext_vector_type(8))) unsigned short u16x8;
using u16 = unsigned short;

#define MFMA16(a, b, c) __builtin_amdgcn_mfma_f32_16x16x32_bf16((a), (b), (c), 0, 0, 0)
#define LOG2E 1.44269504088896f
#define QSCALE (0.125f * 1.44269504088896f)

__device__ __forceinline__ u16 f2bf(float f) {
  union { float f; unsigned int u; } v; v.f = f;
  unsigned int r = v.u + 0x7FFFu + ((v.u >> 16) & 1u);
  return (u16)(r >> 16);
}

__device__ __forceinline__ unsigned cvt_pk_bf16(float lo, float hi) {
  unsigned r;
  asm volatile("v_cvt_pk_bf16_f32 %0, %1, %2" : "=v"(r) : "v"(lo), "v"(hi));
  return r;
}

__device__ __forceinline__ void g2lds16(const void* gsrc, void* ldst) {
  __builtin_amdgcn_global_load_lds(
      (const __attribute__((address_space(1))) unsigned int*)gsrc,
      (__attribute__((address_space(3))) unsigned int*)ldst, 16, 0, 0);
}

// ---------------- merged f32 -> bf16 convert (x, Wq, Wk, Wv, Wo) ----------------
__global__ __launch_bounds__(256) void cvt_all(
    const float* __restrict__ x, const float* __restrict__ wq,
    const float* __restrict__ wk, const float* __restrict__ wv,
    const float* __restrict__ wo, u16* __restrict__ xb,
    u16* __restrict__ w1b, u16* __restrict__ wob) {
  int bid = blockIdx.x, tid = threadIdx.x;
  const float* src; u16* dst; int i;
  if (bid < 2048)      { src = x;  dst = xb;            i = bid * 256 + tid; }
  else if (bid < 2560) { src = wq; dst = w1b;           i = (bid - 2048) * 256 + tid; }
  else if (bid < 3072) { src = wk; dst = w1b + (1<<20); i = (bid - 2560) * 256 + tid; }
  else if (bid < 3584) { src = wv; dst = w1b + (2<<20); i = (bid - 3072) * 256 + tid; }
  else                 { src = wo; dst = wob;           i = (bid - 3584) * 256 + tid; }
  const float4* s = (const float4*)src;
  float4 a = s[2 * i], b = s[2 * i + 1];
  u16x8 o;
  o[0] = f2bf(a.x); o[1] = f2bf(a.y); o[2] = f2bf(a.z); o[3] = f2bf(a.w);
  o[4] = f2bf(b.x); o[5] = f2bf(b.y); o[6] = f2bf(b.z); o[7] = f2bf(b.w);
  ((u16x8*)dst)[i] = o;
}

// ---------------- GEMM C = A * B^T ----------------
// MODE 0: scatter to q/k [B,H,L,HD] bf16 and V^T [B,H,HD,L] bf16 (+bias, q scaled).
// MODE 1: f32 out [M,1024] (+bias).
template <int MODE>
__global__ __launch_bounds__(256, 2) void gemm_bt(
    const u16* __restrict__ A, const u16* __restrict__ B,
    u16* __restrict__ qp, u16* __restrict__ kp, u16* __restrict__ vp,
    const float* __restrict__ b0, const float* __restrict__ b1,
    const float* __restrict__ b2, float* __restrict__ outp,
    const float* __restrict__ bo) {
  __shared__ __align__(16) u16 lA[128 * 64];
  __shared__ __align__(16) u16 lB[128 * 64];
  const int tid = threadIdx.x;
  const int lane = tid & 63, wid = tid >> 6;
  const int g = lane >> 4, cc = lane & 15;
  const int wr = wid >> 1, wc = wid & 1;
  const int m0 = blockIdx.y * 128, n0 = blockIdx.x * 128;
  f32x4 acc[4][4] = {};
  for (int kt = 0; kt < 16; ++kt) {
    const int kof = kt * 64;
#pragma unroll
    for (int i = 0; i < 4; ++i) {
      int cid = i * 256 + tid;
      int row = cid >> 3;
      int col = (cid & 7) * 8;
      g2lds16(A + (size_t)(m0 + row) * 1024 + kof + col, &lA[(i * 256 + wid * 64) * 8]);
      g2lds16(B + (size_t)(n0 + row) * 1024 + kof + col, &lB[(i * 256 + wid * 64) * 8]);
    }
    __syncthreads();
#pragma unroll
    for (int kc = 0; kc < 2; ++kc) {
      bf16x8 af[4], bfr[4];
#pragma unroll
      for (int mf = 0; mf < 4; ++mf)
        af[mf] = *(const bf16x8*)&lA[(wr * 64 + mf * 16 + cc) * 64 + kc * 32 + g * 8];
#pragma unroll
      for (int nf = 0; nf < 4; ++nf)
        bfr[nf] = *(const bf16x8*)&lB[(wc * 64 + nf * 16 + cc) * 64 + kc * 32 + g * 8];
#pragma unroll
      for (int mf = 0; mf < 4; ++mf)
#pragma unroll
        for (int nf = 0; nf < 4; ++nf)
          acc[mf][nf] = MFMA16(af[mf], bfr[nf], acc[mf][nf]);
    }
    __syncthreads();
  }
#pragma unroll
  for (int mf = 0; mf < 4; ++mf) {
#pragma unroll
    for (int nf = 0; nf < 4; ++nf) {
      int n = n0 + wc * 64 + nf * 16 + cc;
      if (MODE == 0) {
        int which = n >> 10;
        int nn = n & 1023;
        const float* bp = which == 0 ? b0 : (which == 1 ? b1 : b2);
        float bias = bp[nn];
        int h = nn >> 6, hd = nn & 63;
        int mb = m0 + wr * 64 + mf * 16 + g * 4;
        int bb = mb >> 11, ll0 = mb & 2047;
        if (which == 2) {
          // V^T fused: [B,H,HD,L]; 4 consecutive L per lane -> 8B store
          ushort4 pk4;
          pk4.x = f2bf(acc[mf][nf][0] + bias);
          pk4.y = f2bf(acc[mf][nf][1] + bias);
          pk4.z = f2bf(acc[mf][nf][2] + bias);
          pk4.w = f2bf(acc[mf][nf][3] + bias);
          *(ushort4*)&vp[(((size_t)(bb * 16 + h)) * 64 + hd) * 2048 + ll0] = pk4;
        } else {
          u16* dp = which == 0 ? qp : kp;
#pragma unroll
          for (int r = 0; r < 4; ++r) {
            float val = acc[mf][nf][r] + bias;
            if (which == 0) val *= QSCALE;
            dp[(((size_t)(bb * 16 + h)) * 2048 + ll0 + r) * 64 + hd] = f2bf(val);
          }
        }
      } else {
        float bias = bo[n];
#pragma unroll
        for (int r = 0; r < 4; ++r) {
          int m = m0 + wr * 64 + mf * 16 + g * 4 + r;
          outp[(size_t)m * 1024 + n] = acc[mf][nf][r] + bias;
        }
      }
    }
  }
}

// ---------------- Flash attention (dbuf LDS K/V, counted vmcnt) ----------------
// Block = 4 waves (batch x strip), 16 q-rows/wave, one head. XCD swizzle: each
// XCD owns 2 heads -> K/V (2MB) fits its L2. Per iter:
//   barrier1 -> stage(t+1)->buf^1 + bias(t+1) -> vmcnt(12) -> barrier2 -> compute(t)
// vmcnt(12) leaves the 12 newest (stage(t+1)+bias(t+1)) in flight; drains
// stage(t) (all older) before barrier2. Per-iter softmax rescale (R3-proven).
__global__ __launch_bounds__(256, 2) void attn_kernel(
    const u16* __restrict__ qm, const u16* __restrict__ km,
    const u16* __restrict__ vtm, const float* __restrict__ bias,
    u16* __restrict__ aout) {
  __shared__ __align__(16) u16 lKV[2][16384];  // dbuf: K(b0) K(b1) VT(b0) VT(b1)
  __shared__ __align__(16) u16 plds[4096];     // per-wave 16x64 P tile
  const int tid = threadIdx.x;
  const int lane = tid & 63, wid = tid >> 6;
  const int g = lane >> 4, cc = lane & 15;
  const int b = wid >> 1, strip = wid & 1;
  // XCD swizzle: xcd = lin&7 owns heads 2*xcd, 2*xcd+1
  const int lin = blockIdx.y * 64 + blockIdx.x;
  const int xcd = lin & 7, j = lin >> 3;
  const int h = xcd * 2 + (j >> 6);
  const int q0 = (j & 63) * 32 + strip * 16;
  const u16* kg0 = km + ((size_t)0 * 16 + h) * 2048 * 64;
  const u16* kg1 = km + ((size_t)1 * 16 + h) * 2048 * 64;
  const u16* vg0 = vtm + ((size_t)0 * 16 + h) * 64 * 2048;
  const u16* vg1 = vtm + ((size_t)1 * 16 + h) * 64 * 2048;
  const size_t bh = (size_t)b * 16 + h;
  const u16* qbase = qm + (bh * 2048 + q0) * 64;
  const float* brow = bias + ((size_t)h * 2048 + q0 + cc) * 2048;
  u16* plw = plds + wid * 1024;

  bf16x8 qf0 = *(const bf16x8*)&qbase[(size_t)cc * 64 + g * 8];
  bf16x8 qf1 = *(const bf16x8*)&qbase[(size_t)cc * 64 + 32 + g * 8];
  f32x4 o[4] = {};
  float mrow = -3.0e38f, lrow = 0.f;

  // stage one 64x64 tile, pre-swizzled global source (chunk ^= row&7), linear LDS
#define STAGE_TILE(gbase, rs, loff)                                            \
  _Pragma("unroll") for (int rep = 0; rep < 2; ++rep) {                        \
    int i = rep * 256 + tid;                                                   \
    int row = i >> 3, pcol = i & 7;                                            \
    int lcol = pcol ^ (row & 7);                                               \
    g2lds16((gbase) + (size_t)row * (rs) + lcol * 8,                           \
            &((u16*)lKV)[(loff) + i * 8]);                                     \
  }

#define STAGE_ALL(P, k0_)                                                      \
  STAGE_TILE(kg0 + (size_t)(k0_) * 64, 64, (P) * 16384 + 0)                    \
  STAGE_TILE(kg1 + (size_t)(k0_) * 64, 64, (P) * 16384 + 4096)                 \
  STAGE_TILE(vg0 + (k0_), 2048, (P) * 16384 + 8192)                            \
  STAGE_TILE(vg1 + (k0_), 2048, (P) * 16384 + 12288)

  float4 bA[4], bB[4];
  // prologue: stage tile 0 -> buf0, bias(0) -> bA
  STAGE_ALL(0, 0)
#pragma unroll
  for (int kb = 0; kb < 4; ++kb)
    bA[kb] = *(const float4*)(brow + kb * 16 + g * 4);

#define ATTN_STEP(P, BC, BN, kt_, DOPRE)                                       \
  {                                                                            \
    const int k0 = (kt_) * 64;                                                 \
    __builtin_amdgcn_sched_barrier(0);                                         \
    __builtin_amdgcn_s_barrier(); /* prev readers of buf P^1 done */           \
    __builtin_amdgcn_sched_barrier(0);                                         \
    if (DOPRE) {                                                               \
      STAGE_ALL((P) ^ 1, k0 + 64)                                              \
      _Pragma("unroll") for (int kb = 0; kb < 4; ++kb)                         \
          BN[kb] = *(const float4*)(brow + k0 + 64 + kb * 16 + g * 4);         \
      __builtin_amdgcn_sched_barrier(0);                                       \
      asm volatile("s_waitcnt vmcnt(12)" ::: "memory");                        \
    } else {                                                                   \
      asm volatile("s_waitcnt vmcnt(0)" ::: "memory");                         \
    }                                                                          \
    __builtin_amdgcn_sched_barrier(0);                                         \
    __builtin_amdgcn_s_barrier(); /* all waves' tile-t stage landed */         \
    __builtin_amdgcn_sched_barrier(0);                                         \
    const u16* lK = &lKV[P][b * 4096];                                         \
    const u16* lV = &lKV[P][8192 + b * 4096];                                  \
    /* S^T = K Q^T : lane(g,cc) -> S[q=cc][k=kb*16+g*4+r] */                   \
    f32x4 s[4];                                                                \
    _Pragma("unroll") for (int kb = 0; kb < 4; ++kb) {                         \
      int row = kb * 16 + cc;                                                  \
      bf16x8 ka = *(const bf16x8*)&lK[row * 64 + ((0 + g) ^ (cc & 7)) * 8];    \
      bf16x8 kbf = *(const bf16x8*)&lK[row * 64 + ((4 + g) ^ (cc & 7)) * 8];   \
      f32x4 z = {};                                                            \
      z = MFMA16(ka, qf0, z);                                                  \
      z = MFMA16(kbf, qf1, z);                                                 \
      s[kb] = z;                                                               \
    }                                                                          \
    _Pragma("unroll") for (int kb = 0; kb < 4; ++kb) {                         \
      s[kb][0] = fmaf(BC[kb].x, LOG2E, s[kb][0]);                              \
      s[kb][1] = fmaf(BC[kb].y, LOG2E, s[kb][1]);                              \
      s[kb][2] = fmaf(BC[kb].z, LOG2E, s[kb][2]);                              \
      s[kb][3] = fmaf(BC[kb].w, LOG2E, s[kb][3]);                              \
    }                                                                          \
    /* online softmax, per-iter rescale (R3-proven) */                         \
    float rmax = s[0][0];                                                      \
    _Pragma("unroll") for (int kb = 0; kb < 4; ++kb)                           \
        _Pragma("unroll") for (int r = 0; r < 4; ++r)                          \
            rmax = fmaxf(rmax, s[kb][r]);                                      \
    rmax = fmaxf(rmax, __shfl_xor(rmax, 16, 64));                              \
    rmax = fmaxf(rmax, __shfl_xor(rmax, 32, 64));                              \
    float mnew = fmaxf(mrow, rmax);                                            \
    float sc = __builtin_amdgcn_exp2f(mrow - mnew);                            \
    mrow = mnew;                                                               \
    float psum = 0.f;                                                          \
    _Pragma("unroll") for (int kb = 0; kb < 4; ++kb)                           \
        _Pragma("unroll") for (int r = 0; r < 4; ++r) {                        \
      s[kb][r] = __builtin_amdgcn_exp2f(s[kb][r] - mrow);                      \
      psum += s[kb][r];                                                        \
    }                                                                          \
    psum += __shfl_xor(psum, 16, 64);                                          \
    psum += __shfl_xor(psum, 32, 64);                                          \
    lrow = lrow * sc + psum;                                                   \
    float scb[4];                                                              \
    _Pragma("unroll") for (int r = 0; r < 4; ++r)                              \
        scb[r] = __shfl(sc, (lane & 48) | (((lane >> 4) & 3) * 4 + r), 64);    \
    _Pragma("unroll") for (int td = 0; td < 4; ++td)                           \
        _Pragma("unroll") for (int r = 0; r < 4; ++r) o[td][r] *= scb[r];      \
    /* P -> wave-private swizzled LDS */                                       \
    _Pragma("unroll") for (int kb = 0; kb < 4; ++kb) {                         \
      unsigned lo = cvt_pk_bf16(s[kb][0], s[kb][1]);                           \
      unsigned hi = cvt_pk_bf16(s[kb][2], s[kb][3]);                           \
      int ch = (kb * 4 + g) ^ ((cc & 7) << 1);                                 \
      ((uint2*)plw)[cc * 16 + ch] = make_uint2(lo, hi);                        \
    }                                                                          \
    bf16x8 pf0 = *(const bf16x8*)&plw[cc * 64 + (((2 * g) ^ ((cc & 7) << 1)) * 4)]; \
    bf16x8 pf1 = *(const bf16x8*)&plw[cc * 64 + (((8 + 2 * g) ^ ((cc & 7) << 1)) * 4)]; \
    _Pragma("unroll") for (int td = 0; td < 4; ++td) {                         \
      int row = td * 16 + cc;                                                  \
      bf16x8 va = *(const bf16x8*)&lV[row * 64 + ((0 + g) ^ (cc & 7)) * 8];    \
      bf16x8 vb = *(const bf16x8*)&lV[row * 64 + ((4 + g) ^ (cc & 7)) * 8];    \
      o[td] = MFMA16(pf0, va, o[td]);                                          \
      o[td] = MFMA16(pf1, vb, o[td]);                                          \
    }                                                                          \
  }

  for (int kt = 0; kt < 30; kt += 2) {
    ATTN_STEP(0, bA, bB, kt, 1)
    ATTN_STEP(1, bB, bA, kt + 1, 1)
  }
  ATTN_STEP(0, bA, bB, 30, 1)   // prefetches tile 31 -> buf1
  ATTN_STEP(1, bB, bA, 31, 0)   // final: vmcnt(0)
#undef ATTN_STEP
#undef STAGE_ALL
#undef STAGE_TILE

  // normalize + write [B, L, 1024] bf16
  float linv = 1.0f / lrow;
  float lb[4];
#pragma unroll
  for (int r = 0; r < 4; ++r)
    lb[r] = __shfl(linv, (lane & 48) | (((lane >> 4) & 3) * 4 + r), 64);
#pragma unroll
  for (int td = 0; td < 4; ++td)
#pragma unroll
    for (int r = 0; r < 4; ++r) {
      float val = o[td][r] * lb[r];
      int qg = q0 + g * 4 + r;
      aout[((size_t)b * 2048 + qg) * 1024 + h * 64 + td * 16 + cc] = f2bf(val);
    }
}

extern "C" void kernel_launch(void* const* d_in, const int* in_sizes, int n_in,
                              void* d_out, int out_size, void* d_ws, size_t ws_size,
                              hipStream_t stream) {
  const float* x  = (const float*)d_in[0];
  const float* rb = (const float*)d_in[1];
  const float* Wq = (const float*)d_in[2];
  const float* bq = (const float*)d_in[3];
  const float* Wk = (const float*)d_in[4];
  const float* bk = (const float*)d_in[5];
  const float* Wv = (const float*)d_in[6];
  const float* bv = (const float*)d_in[7];
  const float* Wo = (const float*)d_in[8];
  const float* bo = (const float*)d_in[9];
  float* out = (float*)d_out;
  char* ws = (char*)d_ws;

  u16* xb   = (u16*)(ws);                 // 8 MB  [4096,1024] bf16 (reused as aout)
  u16* W1b  = (u16*)(ws + (8 << 20));     // 6 MB  [3072,1024] bf16 (Wq|Wk|Wv)
  u16* Wob  = (u16*)(ws + (14 << 20));    // 2 MB  [1024,1024] bf16
  u16* qb   = (u16*)(ws + (16 << 20));    // 8 MB  [B,H,L,HD]
  u16* kb2  = (u16*)(ws + (24 << 20));    // 8 MB  [B,H,L,HD]
  u16* vtb  = (u16*)(ws + (32 << 20));    // 8 MB  [B,H,HD,L] (written by QKV GEMM)
  u16* aout = xb;                         // alias: xb dead after QKV GEMM

  cvt_all<<<4096, 256, 0, stream>>>(x, Wq, Wk, Wv, Wo, xb, W1b, Wob);
  gemm_bt<0><<<dim3(24, 32), 256, 0, stream>>>(xb, W1b, qb, kb2, vtb, bq, bk, bv,
                                               nullptr, nullptr);
  attn_kernel<<<dim3(64, 16), 256, 0, stream>>>(qb, kb2, vtb, rb, aout);
  gemm_bt<1><<<dim3(8, 32), 256, 0, stream>>>(aout, Wob, nullptr, nullptr, nullptr,
                                              nullptr, nullptr, nullptr, out, bo);
}

// Round 6
// 209.169 us; speedup vs baseline: 1.0806x; 1.0806x over previous
//
#include <hip/hip_runtime.h>

// MultiheadAttentionWithBias: B=2, L=2048, D=1024, H=16, HD=64
// cvt_all -> QKV GEMM (V^T fused epilogue) -> flash attn (phase-split
// single-buffer LDS K/V, counted vmcnt, XCD swizzle) -> out GEMM.
// R6: attn restructured: 40KB LDS (4 blk/CU), V staged under QK/softmax,
//     K(t+1) staged under PV. Everything else identical to R5 (passing).

typedef __attribute__((ext_vector_type(8))) short bf16x8;
typedef __attribute__((ext_vector_type(4))) float f32x4;
typedef __attribute__((ext_vector_type(8))) unsigned short u16x8;
using u16 = unsigned short;

#define MFMA16(a, b, c) __builtin_amdgcn_mfma_f32_16x16x32_bf16((a), (b), (c), 0, 0, 0)
#define LOG2E 1.44269504088896f
#define QSCALE (0.125f * 1.44269504088896f)

__device__ __forceinline__ u16 f2bf(float f) {
  union { float f; unsigned int u; } v; v.f = f;
  unsigned int r = v.u + 0x7FFFu + ((v.u >> 16) & 1u);
  return (u16)(r >> 16);
}

__device__ __forceinline__ unsigned cvt_pk_bf16(float lo, float hi) {
  unsigned r;
  asm volatile("v_cvt_pk_bf16_f32 %0, %1, %2" : "=v"(r) : "v"(lo), "v"(hi));
  return r;
}

__device__ __forceinline__ void g2lds16(const void* gsrc, void* ldst) {
  __builtin_amdgcn_global_load_lds(
      (const __attribute__((address_space(1))) unsigned int*)gsrc,
      (__attribute__((address_space(3))) unsigned int*)ldst, 16, 0, 0);
}

// ---------------- merged f32 -> bf16 convert (x, Wq, Wk, Wv, Wo) ----------------
__global__ __launch_bounds__(256) void cvt_all(
    const float* __restrict__ x, const float* __restrict__ wq,
    const float* __restrict__ wk, const float* __restrict__ wv,
    const float* __restrict__ wo, u16* __restrict__ xb,
    u16* __restrict__ w1b, u16* __restrict__ wob) {
  int bid = blockIdx.x, tid = threadIdx.x;
  const float* src; u16* dst; int i;
  if (bid < 2048)      { src = x;  dst = xb;            i = bid * 256 + tid; }
  else if (bid < 2560) { src = wq; dst = w1b;           i = (bid - 2048) * 256 + tid; }
  else if (bid < 3072) { src = wk; dst = w1b + (1<<20); i = (bid - 2560) * 256 + tid; }
  else if (bid < 3584) { src = wv; dst = w1b + (2<<20); i = (bid - 3072) * 256 + tid; }
  else                 { src = wo; dst = wob;           i = (bid - 3584) * 256 + tid; }
  const float4* s = (const float4*)src;
  float4 a = s[2 * i], b = s[2 * i + 1];
  u16x8 o;
  o[0] = f2bf(a.x); o[1] = f2bf(a.y); o[2] = f2bf(a.z); o[3] = f2bf(a.w);
  o[4] = f2bf(b.x); o[5] = f2bf(b.y); o[6] = f2bf(b.z); o[7] = f2bf(b.w);
  ((u16x8*)dst)[i] = o;
}

// ---------------- GEMM C = A * B^T ----------------
// MODE 0: scatter to q/k [B,H,L,HD] bf16 and V^T [B,H,HD,L] bf16 (+bias, q scaled).
// MODE 1: f32 out [M,1024] (+bias).
template <int MODE>
__global__ __launch_bounds__(256, 2) void gemm_bt(
    const u16* __restrict__ A, const u16* __restrict__ B,
    u16* __restrict__ qp, u16* __restrict__ kp, u16* __restrict__ vp,
    const float* __restrict__ b0, const float* __restrict__ b1,
    const float* __restrict__ b2, float* __restrict__ outp,
    const float* __restrict__ bo) {
  __shared__ __align__(16) u16 lA[128 * 64];
  __shared__ __align__(16) u16 lB[128 * 64];
  const int tid = threadIdx.x;
  const int lane = tid & 63, wid = tid >> 6;
  const int g = lane >> 4, cc = lane & 15;
  const int wr = wid >> 1, wc = wid & 1;
  const int m0 = blockIdx.y * 128, n0 = blockIdx.x * 128;
  f32x4 acc[4][4] = {};
  for (int kt = 0; kt < 16; ++kt) {
    const int kof = kt * 64;
#pragma unroll
    for (int i = 0; i < 4; ++i) {
      int cid = i * 256 + tid;
      int row = cid >> 3;
      int col = (cid & 7) * 8;
      g2lds16(A + (size_t)(m0 + row) * 1024 + kof + col, &lA[(i * 256 + wid * 64) * 8]);
      g2lds16(B + (size_t)(n0 + row) * 1024 + kof + col, &lB[(i * 256 + wid * 64) * 8]);
    }
    __syncthreads();
#pragma unroll
    for (int kc = 0; kc < 2; ++kc) {
      bf16x8 af[4], bfr[4];
#pragma unroll
      for (int mf = 0; mf < 4; ++mf)
        af[mf] = *(const bf16x8*)&lA[(wr * 64 + mf * 16 + cc) * 64 + kc * 32 + g * 8];
#pragma unroll
      for (int nf = 0; nf < 4; ++nf)
        bfr[nf] = *(const bf16x8*)&lB[(wc * 64 + nf * 16 + cc) * 64 + kc * 32 + g * 8];
#pragma unroll
      for (int mf = 0; mf < 4; ++mf)
#pragma unroll
        for (int nf = 0; nf < 4; ++nf)
          acc[mf][nf] = MFMA16(af[mf], bfr[nf], acc[mf][nf]);
    }
    __syncthreads();
  }
#pragma unroll
  for (int mf = 0; mf < 4; ++mf) {
#pragma unroll
    for (int nf = 0; nf < 4; ++nf) {
      int n = n0 + wc * 64 + nf * 16 + cc;
      if (MODE == 0) {
        int which = n >> 10;
        int nn = n & 1023;
        const float* bp = which == 0 ? b0 : (which == 1 ? b1 : b2);
        float bias = bp[nn];
        int h = nn >> 6, hd = nn & 63;
        int mb = m0 + wr * 64 + mf * 16 + g * 4;
        int bb = mb >> 11, ll0 = mb & 2047;
        if (which == 2) {
          // V^T fused: [B,H,HD,L]; 4 consecutive L per lane -> 8B store
          ushort4 pk4;
          pk4.x = f2bf(acc[mf][nf][0] + bias);
          pk4.y = f2bf(acc[mf][nf][1] + bias);
          pk4.z = f2bf(acc[mf][nf][2] + bias);
          pk4.w = f2bf(acc[mf][nf][3] + bias);
          *(ushort4*)&vp[(((size_t)(bb * 16 + h)) * 64 + hd) * 2048 + ll0] = pk4;
        } else {
          u16* dp = which == 0 ? qp : kp;
#pragma unroll
          for (int r = 0; r < 4; ++r) {
            float val = acc[mf][nf][r] + bias;
            if (which == 0) val *= QSCALE;
            dp[(((size_t)(bb * 16 + h)) * 2048 + ll0 + r) * 64 + hd] = f2bf(val);
          }
        }
      } else {
        float bias = bo[n];
#pragma unroll
        for (int r = 0; r < 4; ++r) {
          int m = m0 + wr * 64 + mf * 16 + g * 4 + r;
          outp[(size_t)m * 1024 + n] = acc[mf][nf][r] + bias;
        }
      }
    }
  }
}

// ---------------- Flash attention (phase-split single-buffer LDS) ----------------
// Block = 4 waves (batch x strip), 16 q-rows/wave, one head. 40KB LDS -> 4 blk/CU.
// Per iter: barrier -> stage V(t) -> QK^T(lK)+softmax (V in flight under it)
//   -> vmcnt(0) -> barrier -> stage K(t+1)+bias(t+1) -> P->LDS, PV(lV)
//   -> vmcnt(4) (drains K(t+1), leaves 4 bias loads in flight).
// Race-safety: lV overwrite fenced by barrier-1 (prev PV done); lK overwrite
// fenced by barrier-2 (QK reads done). XCD swizzle: xcd owns heads 2x,2x+1.
__global__ __launch_bounds__(256, 4) void attn_kernel(
    const u16* __restrict__ qm, const u16* __restrict__ km,
    const u16* __restrict__ vtm, const float* __restrict__ bias,
    u16* __restrict__ aout) {
  __shared__ __align__(16) u16 lK[2][4096];   // K(b0),K(b1): 16KB
  __shared__ __align__(16) u16 lV[2][4096];   // VT(b0),VT(b1): 16KB
  __shared__ __align__(16) u16 plds[4096];    // per-wave 16x64 P tile: 8KB
  const int tid = threadIdx.x;
  const int lane = tid & 63, wid = tid >> 6;
  const int g = lane >> 4, cc = lane & 15;
  const int b = wid >> 1, strip = wid & 1;
  // XCD swizzle: xcd = lin&7 owns heads 2*xcd, 2*xcd+1
  const int lin = blockIdx.y * 64 + blockIdx.x;
  const int xcd = lin & 7, j = lin >> 3;
  const int h = xcd * 2 + (j >> 6);
  const int q0 = (j & 63) * 32 + strip * 16;
  const u16* kg0 = km + ((size_t)0 * 16 + h) * 2048 * 64;
  const u16* kg1 = km + ((size_t)1 * 16 + h) * 2048 * 64;
  const u16* vg0 = vtm + ((size_t)0 * 16 + h) * 64 * 2048;
  const u16* vg1 = vtm + ((size_t)1 * 16 + h) * 64 * 2048;
  const size_t bh = (size_t)b * 16 + h;
  const u16* qbase = qm + (bh * 2048 + q0) * 64;
  const float* brow = bias + ((size_t)h * 2048 + q0 + cc) * 2048;
  u16* plw = plds + wid * 1024;

  bf16x8 qf0 = *(const bf16x8*)&qbase[(size_t)cc * 64 + g * 8];
  bf16x8 qf1 = *(const bf16x8*)&qbase[(size_t)cc * 64 + 32 + g * 8];
  f32x4 o[4] = {};
  float mrow = -3.0e38f, lrow = 0.f;

  // stage one 64x64 tile, pre-swizzled global source (chunk ^= row&7), linear LDS
#define STAGE_TILE(gbase, rs, ldst)                                            \
  _Pragma("unroll") for (int rep = 0; rep < 2; ++rep) {                        \
    int i = rep * 256 + tid;                                                   \
    int row = i >> 3, pcol = i & 7;                                            \
    int lcol = pcol ^ (row & 7);                                               \
    g2lds16((gbase) + (size_t)row * (rs) + lcol * 8, (ldst) + i * 8);          \
  }

  float4 bA[4];
  // prologue: stage K(0) -> lK (oldest 4 ops), then bias(0) (newest 4)
  STAGE_TILE(kg0, 64, (u16*)&lK[0][0])
  STAGE_TILE(kg1, 64, (u16*)&lK[1][0])
  __builtin_amdgcn_sched_barrier(0);
#pragma unroll
  for (int kb = 0; kb < 4; ++kb)
    bA[kb] = *(const float4*)(brow + kb * 16 + g * 4);
  __builtin_amdgcn_sched_barrier(0);
  asm volatile("s_waitcnt vmcnt(4)" ::: "memory");  // K(0) landed, bias flying
  __builtin_amdgcn_sched_barrier(0);

#define ATTN_STEP(kt_, DOPRE)                                                  \
  {                                                                            \
    const int k0 = (kt_) * 64;                                                 \
    __builtin_amdgcn_s_barrier(); /* prev PV done (lV free); K(t) landed */    \
    __builtin_amdgcn_sched_barrier(0);                                         \
    /* stage V(t) -> lV; flies under QK^T+softmax */                           \
    STAGE_TILE(vg0 + k0, 2048, (u16*)&lV[0][0])                                \
    STAGE_TILE(vg1 + k0, 2048, (u16*)&lV[1][0])                                \
    __builtin_amdgcn_sched_barrier(0);                                         \
    /* S^T = K Q^T : lane(g,cc) -> S[q=cc][k=kb*16+g*4+r] */                   \
    f32x4 s[4];                                                                \
    _Pragma("unroll") for (int kb = 0; kb < 4; ++kb) {                         \
      int row = kb * 16 + cc;                                                  \
      bf16x8 ka = *(const bf16x8*)&lK[b][row * 64 + ((0 + g) ^ (cc & 7)) * 8]; \
      bf16x8 kbf = *(const bf16x8*)&lK[b][row * 64 + ((4 + g) ^ (cc & 7)) * 8];\
      f32x4 z = {};                                                            \
      z = MFMA16(ka, qf0, z);                                                  \
      z = MFMA16(kbf, qf1, z);                                                 \
      s[kb] = z;                                                               \
    }                                                                          \
    _Pragma("unroll") for (int kb = 0; kb < 4; ++kb) {                         \
      s[kb][0] = fmaf(bA[kb].x, LOG2E, s[kb][0]);                              \
      s[kb][1] = fmaf(bA[kb].y, LOG2E, s[kb][1]);                              \
      s[kb][2] = fmaf(bA[kb].z, LOG2E, s[kb][2]);                              \
      s[kb][3] = fmaf(bA[kb].w, LOG2E, s[kb][3]);                              \
    }                                                                          \
    /* online softmax, per-iter rescale (R3-proven) */                         \
    float rmax = s[0][0];                                                      \
    _Pragma("unroll") for (int kb = 0; kb < 4; ++kb)                           \
        _Pragma("unroll") for (int r = 0; r < 4; ++r)                          \
            rmax = fmaxf(rmax, s[kb][r]);                                      \
    rmax = fmaxf(rmax, __shfl_xor(rmax, 16, 64));                              \
    rmax = fmaxf(rmax, __shfl_xor(rmax, 32, 64));                              \
    float mnew = fmaxf(mrow, rmax);                                            \
    float sc = __builtin_amdgcn_exp2f(mrow - mnew);                            \
    mrow = mnew;                                                               \
    float psum = 0.f;                                                          \
    _Pragma("unroll") for (int kb = 0; kb < 4; ++kb)                           \
        _Pragma("unroll") for (int r = 0; r < 4; ++r) {                        \
      s[kb][r] = __builtin_amdgcn_exp2f(s[kb][r] - mrow);                      \
      psum += s[kb][r];                                                        \
    }                                                                          \
    psum += __shfl_xor(psum, 16, 64);                                          \
    psum += __shfl_xor(psum, 32, 64);                                          \
    lrow = lrow * sc + psum;                                                   \
    float scb[4];                                                              \
    _Pragma("unroll") for (int r = 0; r < 4; ++r)                              \
        scb[r] = __shfl(sc, (lane & 48) | (((lane >> 4) & 3) * 4 + r), 64);    \
    _Pragma("unroll") for (int td = 0; td < 4; ++td)                           \
        _Pragma("unroll") for (int r = 0; r < 4; ++r) o[td][r] *= scb[r];      \
    /* V(t) landed?  drain stage (4 ops outstanding), then block barrier */    \
    __builtin_amdgcn_sched_barrier(0);                                         \
    asm volatile("s_waitcnt vmcnt(0)" ::: "memory");                           \
    __builtin_amdgcn_sched_barrier(0);                                         \
    __builtin_amdgcn_s_barrier(); /* QK reads done (lK free); V(t) visible */  \
    __builtin_amdgcn_sched_barrier(0);                                         \
    if (DOPRE) {                                                               \
      /* stage K(t+1) -> lK (oldest), bias(t+1) -> bA (newest) */              \
      STAGE_TILE(kg0 + (size_t)(k0 + 64) * 64, 64, (u16*)&lK[0][0])            \
      STAGE_TILE(kg1 + (size_t)(k0 + 64) * 64, 64, (u16*)&lK[1][0])            \
      __builtin_amdgcn_sched_barrier(0);                                       \
      _Pragma("unroll") for (int kb = 0; kb < 4; ++kb)                         \
          bA[kb] = *(const float4*)(brow + k0 + 64 + kb * 16 + g * 4);         \
      __builtin_amdgcn_sched_barrier(0);                                       \
    }                                                                          \
    /* P -> wave-private swizzled LDS -> A-frags */                            \
    _Pragma("unroll") for (int kb = 0; kb < 4; ++kb) {                         \
      unsigned lo = cvt_pk_bf16(s[kb][0], s[kb][1]);                           \
      unsigned hi = cvt_pk_bf16(s[kb][2], s[kb][3]);                           \
      int ch = (kb * 4 + g) ^ ((cc & 7) << 1);                                 \
      ((uint2*)plw)[cc * 16 + ch] = make_uint2(lo, hi);                        \
    }                                                                          \
    bf16x8 pf0 = *(const bf16x8*)&plw[cc * 64 + (((2 * g) ^ ((cc & 7) << 1)) * 4)]; \
    bf16x8 pf1 = *(const bf16x8*)&plw[cc * 64 + (((8 + 2 * g) ^ ((cc & 7) << 1)) * 4)]; \
    _Pragma("unroll") for (int td = 0; td < 4; ++td) {                         \
      int row = td * 16 + cc;                                                  \
      bf16x8 va = *(const bf16x8*)&lV[b][row * 64 + ((0 + g) ^ (cc & 7)) * 8]; \
      bf16x8 vb = *(const bf16x8*)&lV[b][row * 64 + ((4 + g) ^ (cc & 7)) * 8]; \
      o[td] = MFMA16(pf0, va, o[td]);                                          \
      o[td] = MFMA16(pf1, vb, o[td]);                                          \
    }                                                                          \
    /* drain K(t+1) (4 oldest), keep bias(t+1) (4 newest) in flight */         \
    __builtin_amdgcn_sched_barrier(0);                                         \
    if (DOPRE) { asm volatile("s_waitcnt vmcnt(4)" ::: "memory"); }            \
    else       { asm volatile("s_waitcnt vmcnt(0)" ::: "memory"); }            \
    __builtin_amdgcn_sched_barrier(0);                                         \
  }

  for (int kt = 0; kt < 31; ++kt) {
    ATTN_STEP(kt, 1)
  }
  ATTN_STEP(31, 0)
#undef ATTN_STEP
#undef STAGE_TILE

  // normalize + write [B, L, 1024] bf16
  float linv = 1.0f / lrow;
  float lb[4];
#pragma unroll
  for (int r = 0; r < 4; ++r)
    lb[r] = __shfl(linv, (lane & 48) | (((lane >> 4) & 3) * 4 + r), 64);
#pragma unroll
  for (int td = 0; td < 4; ++td)
#pragma unroll
    for (int r = 0; r < 4; ++r) {
      float val = o[td][r] * lb[r];
      int qg = q0 + g * 4 + r;
      aout[((size_t)b * 2048 + qg) * 1024 + h * 64 + td * 16 + cc] = f2bf(val);
    }
}

extern "C" void kernel_launch(void* const* d_in, const int* in_sizes, int n_in,
                              void* d_out, int out_size, void* d_ws, size_t ws_size,
                              hipStream_t stream) {
  const float* x  = (const float*)d_in[0];
  const float* rb = (const float*)d_in[1];
  const float* Wq = (const float*)d_in[2];
  const float* bq = (const float*)d_in[3];
  const float* Wk = (const float*)d_in[4];
  const float* bk = (const float*)d_in[5];
  const float* Wv = (const float*)d_in[6];
  const float* bv = (const float*)d_in[7];
  const float* Wo = (const float*)d_in[8];
  const float* bo = (const float*)d_in[9];
  float* out = (float*)d_out;
  char* ws = (char*)d_ws;

  u16* xb   = (u16*)(ws);                 // 8 MB  [4096,1024] bf16 (reused as aout)
  u16* W1b  = (u16*)(ws + (8 << 20));     // 6 MB  [3072,1024] bf16 (Wq|Wk|Wv)
  u16* Wob  = (u16*)(ws + (14 << 20));    // 2 MB  [1024,1024] bf16
  u16* qb   = (u16*)(ws + (16 << 20));    // 8 MB  [B,H,L,HD]
  u16* kb2  = (u16*)(ws + (24 << 20));    // 8 MB  [B,H,L,HD]
  u16* vtb  = (u16*)(ws + (32 << 20));    // 8 MB  [B,H,HD,L] (written by QKV GEMM)
  u16* aout = xb;                         // alias: xb dead after QKV GEMM

  cvt_all<<<4096, 256, 0, stream>>>(x, Wq, Wk, Wv, Wo, xb, W1b, Wob);
  gemm_bt<0><<<dim3(24, 32), 256, 0, stream>>>(xb, W1b, qb, kb2, vtb, bq, bk, bv,
                                               nullptr, nullptr);
  attn_kernel<<<dim3(64, 16), 256, 0, stream>>>(qb, kb2, vtb, rb, aout);
  gemm_bt<1><<<dim3(8, 32), 256, 0, stream>>>(aout, Wob, nullptr, nullptr, nullptr,
                                              nullptr, nullptr, nullptr, out, bo);
}

// Round 7
// 176.681 us; speedup vs baseline: 1.2793x; 1.1839x over previous
//
#include <hip/hip_runtime.h>

// MultiheadAttentionWithBias: B=2, L=2048, D=1024, H=16, HD=64
// cvt_all -> QKV GEMM (V^T fused epilogue) -> flash attn (one batch/block,
// 8 waves, 128 q-rows, single K/V stage shared by 8 waves, bias read once,
// phase-split counted-vmcnt schedule, XCD swizzle) -> out GEMM.
// R7: attn work-decomposition change only; schedule template = R6 (passing).

typedef __attribute__((ext_vector_type(8))) short bf16x8;
typedef __attribute__((ext_vector_type(4))) float f32x4;
typedef __attribute__((ext_vector_type(8))) unsigned short u16x8;
using u16 = unsigned short;

#define MFMA16(a, b, c) __builtin_amdgcn_mfma_f32_16x16x32_bf16((a), (b), (c), 0, 0, 0)
#define LOG2E 1.44269504088896f
#define QSCALE (0.125f * 1.44269504088896f)

__device__ __forceinline__ u16 f2bf(float f) {
  union { float f; unsigned int u; } v; v.f = f;
  unsigned int r = v.u + 0x7FFFu + ((v.u >> 16) & 1u);
  return (u16)(r >> 16);
}

__device__ __forceinline__ unsigned cvt_pk_bf16(float lo, float hi) {
  unsigned r;
  asm volatile("v_cvt_pk_bf16_f32 %0, %1, %2" : "=v"(r) : "v"(lo), "v"(hi));
  return r;
}

__device__ __forceinline__ void g2lds16(const void* gsrc, void* ldst) {
  __builtin_amdgcn_global_load_lds(
      (const __attribute__((address_space(1))) unsigned int*)gsrc,
      (__attribute__((address_space(3))) unsigned int*)ldst, 16, 0, 0);
}

// ---------------- merged f32 -> bf16 convert (x, Wq, Wk, Wv, Wo) ----------------
__global__ __launch_bounds__(256) void cvt_all(
    const float* __restrict__ x, const float* __restrict__ wq,
    const float* __restrict__ wk, const float* __restrict__ wv,
    const float* __restrict__ wo, u16* __restrict__ xb,
    u16* __restrict__ w1b, u16* __restrict__ wob) {
  int bid = blockIdx.x, tid = threadIdx.x;
  const float* src; u16* dst; int i;
  if (bid < 2048)      { src = x;  dst = xb;            i = bid * 256 + tid; }
  else if (bid < 2560) { src = wq; dst = w1b;           i = (bid - 2048) * 256 + tid; }
  else if (bid < 3072) { src = wk; dst = w1b + (1<<20); i = (bid - 2560) * 256 + tid; }
  else if (bid < 3584) { src = wv; dst = w1b + (2<<20); i = (bid - 3072) * 256 + tid; }
  else                 { src = wo; dst = wob;           i = (bid - 3584) * 256 + tid; }
  const float4* s = (const float4*)src;
  float4 a = s[2 * i], b = s[2 * i + 1];
  u16x8 o;
  o[0] = f2bf(a.x); o[1] = f2bf(a.y); o[2] = f2bf(a.z); o[3] = f2bf(a.w);
  o[4] = f2bf(b.x); o[5] = f2bf(b.y); o[6] = f2bf(b.z); o[7] = f2bf(b.w);
  ((u16x8*)dst)[i] = o;
}

// ---------------- GEMM C = A * B^T ----------------
// MODE 0: scatter to q/k [B,H,L,HD] bf16 and V^T [B,H,HD,L] bf16 (+bias, q scaled).
// MODE 1: f32 out [M,1024] (+bias).
template <int MODE>
__global__ __launch_bounds__(256, 2) void gemm_bt(
    const u16* __restrict__ A, const u16* __restrict__ B,
    u16* __restrict__ qp, u16* __restrict__ kp, u16* __restrict__ vp,
    const float* __restrict__ b0, const float* __restrict__ b1,
    const float* __restrict__ b2, float* __restrict__ outp,
    const float* __restrict__ bo) {
  __shared__ __align__(16) u16 lA[128 * 64];
  __shared__ __align__(16) u16 lB[128 * 64];
  const int tid = threadIdx.x;
  const int lane = tid & 63, wid = tid >> 6;
  const int g = lane >> 4, cc = lane & 15;
  const int wr = wid >> 1, wc = wid & 1;
  const int m0 = blockIdx.y * 128, n0 = blockIdx.x * 128;
  f32x4 acc[4][4] = {};
  for (int kt = 0; kt < 16; ++kt) {
    const int kof = kt * 64;
#pragma unroll
    for (int i = 0; i < 4; ++i) {
      int cid = i * 256 + tid;
      int row = cid >> 3;
      int col = (cid & 7) * 8;
      g2lds16(A + (size_t)(m0 + row) * 1024 + kof + col, &lA[(i * 256 + wid * 64) * 8]);
      g2lds16(B + (size_t)(n0 + row) * 1024 + kof + col, &lB[(i * 256 + wid * 64) * 8]);
    }
    __syncthreads();
#pragma unroll
    for (int kc = 0; kc < 2; ++kc) {
      bf16x8 af[4], bfr[4];
#pragma unroll
      for (int mf = 0; mf < 4; ++mf)
        af[mf] = *(const bf16x8*)&lA[(wr * 64 + mf * 16 + cc) * 64 + kc * 32 + g * 8];
#pragma unroll
      for (int nf = 0; nf < 4; ++nf)
        bfr[nf] = *(const bf16x8*)&lB[(wc * 64 + nf * 16 + cc) * 64 + kc * 32 + g * 8];
#pragma unroll
      for (int mf = 0; mf < 4; ++mf)
#pragma unroll
        for (int nf = 0; nf < 4; ++nf)
          acc[mf][nf] = MFMA16(af[mf], bfr[nf], acc[mf][nf]);
    }
    __syncthreads();
  }
#pragma unroll
  for (int mf = 0; mf < 4; ++mf) {
#pragma unroll
    for (int nf = 0; nf < 4; ++nf) {
      int n = n0 + wc * 64 + nf * 16 + cc;
      if (MODE == 0) {
        int which = n >> 10;
        int nn = n & 1023;
        const float* bp = which == 0 ? b0 : (which == 1 ? b1 : b2);
        float bias = bp[nn];
        int h = nn >> 6, hd = nn & 63;
        int mb = m0 + wr * 64 + mf * 16 + g * 4;
        int bb = mb >> 11, ll0 = mb & 2047;
        if (which == 2) {
          // V^T fused: [B,H,HD,L]; 4 consecutive L per lane -> 8B store
          ushort4 pk4;
          pk4.x = f2bf(acc[mf][nf][0] + bias);
          pk4.y = f2bf(acc[mf][nf][1] + bias);
          pk4.z = f2bf(acc[mf][nf][2] + bias);
          pk4.w = f2bf(acc[mf][nf][3] + bias);
          *(ushort4*)&vp[(((size_t)(bb * 16 + h)) * 64 + hd) * 2048 + ll0] = pk4;
        } else {
          u16* dp = which == 0 ? qp : kp;
#pragma unroll
          for (int r = 0; r < 4; ++r) {
            float val = acc[mf][nf][r] + bias;
            if (which == 0) val *= QSCALE;
            dp[(((size_t)(bb * 16 + h)) * 2048 + ll0 + r) * 64 + hd] = f2bf(val);
          }
        }
      } else {
        float bias = bo[n];
#pragma unroll
        for (int r = 0; r < 4; ++r) {
          int m = m0 + wr * 64 + mf * 16 + g * 4 + r;
          outp[(size_t)m * 1024 + n] = acc[mf][nf][r] + bias;
        }
      }
    }
  }
}

// ---------------- Flash attention (one batch/block, 8 waves, 128 q-rows) --------
// Block = 8 waves (512 thr), ONE (batch, head, 128-q-row strip). Wave wid owns
// q rows [q0+wid*16, +16). Per iter: ONE 64x64 K tile + ONE V^T tile staged for
// all 8 waves; bias (the HBM stream) read once per (q,k) -- no duplicate reads.
// Schedule (R6-proven): barrier -> stage V(t) -> QK^T(lK)+softmax -> vmcnt(0)
//   -> barrier -> stage K(t+1)(1 instr)+bias(t+1)(4) -> P->LDS->PV(lV)
//   -> vmcnt(4) (drains K(t+1), leaves 4 bias loads in flight).
// XCD swizzle: xcd owns heads 2x,2x+1 -> K/V 2MB per XCD L2.
__global__ __launch_bounds__(512, 4) void attn_kernel(
    const u16* __restrict__ qm, const u16* __restrict__ km,
    const u16* __restrict__ vtm, const float* __restrict__ bias,
    u16* __restrict__ aout) {
  __shared__ __align__(16) u16 lK[4096];    // 64x64 K tile: 8KB
  __shared__ __align__(16) u16 lV[4096];    // 64x64 V^T tile: 8KB
  __shared__ __align__(16) u16 plds[8192];  // 8 waves x 16x64 P tile: 16KB
  const int tid = threadIdx.x;
  const int lane = tid & 63, wid = tid >> 6;
  const int g = lane >> 4, cc = lane & 15;
  // XCD swizzle: 512 blocks, xcd = lin&7 owns heads 2*xcd, 2*xcd+1
  const int lin = blockIdx.x;
  const int xcd = lin & 7, j = lin >> 3;          // j in [0,64)
  const int h = xcd * 2 + (j >> 5);
  const int rem = j & 31;
  const int b = rem >> 4, qb = rem & 15;
  const int q0 = qb * 128;
  const size_t bh = (size_t)b * 16 + h;
  const u16* kg = km + bh * 2048 * 64;
  const u16* vg = vtm + bh * 64 * 2048;
  const u16* qbase = qm + (bh * 2048 + q0 + wid * 16) * 64;
  const float* brow = bias + ((size_t)h * 2048 + q0 + wid * 16 + cc) * 2048;
  u16* plw = plds + wid * 1024;

  bf16x8 qf0 = *(const bf16x8*)&qbase[(size_t)cc * 64 + g * 8];
  bf16x8 qf1 = *(const bf16x8*)&qbase[(size_t)cc * 64 + 32 + g * 8];
  f32x4 o[4] = {};
  float mrow = -3.0e38f, lrow = 0.f;

  // stage one 64x64 tile with 512 threads (1 g2lds each), pre-swizzled source
#define STAGE_TILE(gbase, rs, ldst)                                            \
  {                                                                            \
    int row = tid >> 3, pcol = tid & 7;                                        \
    int lcol = pcol ^ (row & 7);                                               \
    g2lds16((gbase) + (size_t)row * (rs) + lcol * 8, (ldst) + tid * 8);        \
  }

  float4 bA[4];
  // prologue: stage K(0) (oldest 1 op), then bias(0) (newest 4)
  STAGE_TILE(kg, 64, (u16*)lK)
  __builtin_amdgcn_sched_barrier(0);
#pragma unroll
  for (int kb = 0; kb < 4; ++kb)
    bA[kb] = *(const float4*)(brow + kb * 16 + g * 4);
  __builtin_amdgcn_sched_barrier(0);
  asm volatile("s_waitcnt vmcnt(4)" ::: "memory");  // K(0) landed, bias flying
  __builtin_amdgcn_sched_barrier(0);

#define ATTN_STEP(kt_, DOPRE)                                                  \
  {                                                                            \
    const int k0 = (kt_) * 64;                                                 \
    __builtin_amdgcn_s_barrier(); /* prev PV done (lV free); K(t) landed */    \
    __builtin_amdgcn_sched_barrier(0);                                         \
    /* stage V(t) -> lV; flies under QK^T+softmax */                           \
    STAGE_TILE(vg + k0, 2048, (u16*)lV)                                        \
    __builtin_amdgcn_sched_barrier(0);                                         \
    /* S^T = K Q^T : lane(g,cc) -> S[q=cc][k=kb*16+g*4+r] */                   \
    f32x4 s[4];                                                                \
    _Pragma("unroll") for (int kb = 0; kb < 4; ++kb) {                         \
      int row = kb * 16 + cc;                                                  \
      bf16x8 ka = *(const bf16x8*)&lK[row * 64 + ((0 + g) ^ (cc & 7)) * 8];    \
      bf16x8 kbf = *(const bf16x8*)&lK[row * 64 + ((4 + g) ^ (cc & 7)) * 8];   \
      f32x4 z = {};                                                            \
      z = MFMA16(ka, qf0, z);                                                  \
      z = MFMA16(kbf, qf1, z);                                                 \
      s[kb] = z;                                                               \
    }                                                                          \
    _Pragma("unroll") for (int kb = 0; kb < 4; ++kb) {                         \
      s[kb][0] = fmaf(bA[kb].x, LOG2E, s[kb][0]);                              \
      s[kb][1] = fmaf(bA[kb].y, LOG2E, s[kb][1]);                              \
      s[kb][2] = fmaf(bA[kb].z, LOG2E, s[kb][2]);                              \
      s[kb][3] = fmaf(bA[kb].w, LOG2E, s[kb][3]);                              \
    }                                                                          \
    /* online softmax, per-iter rescale (R3-proven) */                         \
    float rmax = s[0][0];                                                      \
    _Pragma("unroll") for (int kb = 0; kb < 4; ++kb)                           \
        _Pragma("unroll") for (int r = 0; r < 4; ++r)                          \
            rmax = fmaxf(rmax, s[kb][r]);                                      \
    rmax = fmaxf(rmax, __shfl_xor(rmax, 16, 64));                              \
    rmax = fmaxf(rmax, __shfl_xor(rmax, 32, 64));                              \
    float mnew = fmaxf(mrow, rmax);                                            \
    float sc = __builtin_amdgcn_exp2f(mrow - mnew);                            \
    mrow = mnew;                                                               \
    float psum = 0.f;                                                          \
    _Pragma("unroll") for (int kb = 0; kb < 4; ++kb)                           \
        _Pragma("unroll") for (int r = 0; r < 4; ++r) {                        \
      s[kb][r] = __builtin_amdgcn_exp2f(s[kb][r] - mrow);                      \
      psum += s[kb][r];                                                        \
    }                                                                          \
    psum += __shfl_xor(psum, 16, 64);                                          \
    psum += __shfl_xor(psum, 32, 64);                                          \
    lrow = lrow * sc + psum;                                                   \
    float scb[4];                                                              \
    _Pragma("unroll") for (int r = 0; r < 4; ++r)                              \
        scb[r] = __shfl(sc, (lane & 48) | (((lane >> 4) & 3) * 4 + r), 64);    \
    _Pragma("unroll") for (int td = 0; td < 4; ++td)                           \
        _Pragma("unroll") for (int r = 0; r < 4; ++r) o[td][r] *= scb[r];      \
    /* drain V(t) stage, then block barrier (lK free, V visible) */            \
    __builtin_amdgcn_sched_barrier(0);                                         \
    asm volatile("s_waitcnt vmcnt(0)" ::: "memory");                           \
    __builtin_amdgcn_sched_barrier(0);                                         \
    __builtin_amdgcn_s_barrier();                                              \
    __builtin_amdgcn_sched_barrier(0);                                         \
    if (DOPRE) {                                                               \
      /* stage K(t+1) -> lK (oldest 1), bias(t+1) -> bA (newest 4) */          \
      STAGE_TILE(kg + (size_t)(k0 + 64) * 64, 64, (u16*)lK)                    \
      __builtin_amdgcn_sched_barrier(0);                                       \
      _Pragma("unroll") for (int kb = 0; kb < 4; ++kb)                         \
          bA[kb] = *(const float4*)(brow + k0 + 64 + kb * 16 + g * 4);         \
      __builtin_amdgcn_sched_barrier(0);                                       \
    }                                                                          \
    /* P -> wave-private swizzled LDS -> A-frags */                            \
    _Pragma("unroll") for (int kb = 0; kb < 4; ++kb) {                         \
      unsigned lo = cvt_pk_bf16(s[kb][0], s[kb][1]);                           \
      unsigned hi = cvt_pk_bf16(s[kb][2], s[kb][3]);                           \
      int ch = (kb * 4 + g) ^ ((cc & 7) << 1);                                 \
      ((uint2*)plw)[cc * 16 + ch] = make_uint2(lo, hi);                        \
    }                                                                          \
    bf16x8 pf0 = *(const bf16x8*)&plw[cc * 64 + (((2 * g) ^ ((cc & 7) << 1)) * 4)]; \
    bf16x8 pf1 = *(const bf16x8*)&plw[cc * 64 + (((8 + 2 * g) ^ ((cc & 7) << 1)) * 4)]; \
    _Pragma("unroll") for (int td = 0; td < 4; ++td) {                         \
      int row = td * 16 + cc;                                                  \
      bf16x8 va = *(const bf16x8*)&lV[row * 64 + ((0 + g) ^ (cc & 7)) * 8];    \
      bf16x8 vb = *(const bf16x8*)&lV[row * 64 + ((4 + g) ^ (cc & 7)) * 8];    \
      o[td] = MFMA16(pf0, va, o[td]);                                          \
      o[td] = MFMA16(pf1, vb, o[td]);                                          \
    }                                                                          \
    /* drain K(t+1) (oldest 1 of 5), keep 4 bias loads in flight */            \
    __builtin_amdgcn_sched_barrier(0);                                         \
    if (DOPRE) { asm volatile("s_waitcnt vmcnt(4)" ::: "memory"); }            \
    else       { asm volatile("s_waitcnt vmcnt(0)" ::: "memory"); }            \
    __builtin_amdgcn_sched_barrier(0);                                         \
  }

  for (int kt = 0; kt < 31; ++kt) {
    ATTN_STEP(kt, 1)
  }
  ATTN_STEP(31, 0)
#undef ATTN_STEP
#undef STAGE_TILE

  // normalize + write [B, L, 1024] bf16
  float linv = 1.0f / lrow;
  float lb[4];
#pragma unroll
  for (int r = 0; r < 4; ++r)
    lb[r] = __shfl(linv, (lane & 48) | (((lane >> 4) & 3) * 4 + r), 64);
#pragma unroll
  for (int td = 0; td < 4; ++td)
#pragma unroll
    for (int r = 0; r < 4; ++r) {
      float val = o[td][r] * lb[r];
      int qg = q0 + wid * 16 + g * 4 + r;
      aout[((size_t)b * 2048 + qg) * 1024 + h * 64 + td * 16 + cc] = f2bf(val);
    }
}

extern "C" void kernel_launch(void* const* d_in, const int* in_sizes, int n_in,
                              void* d_out, int out_size, void* d_ws, size_t ws_size,
                              hipStream_t stream) {
  const float* x  = (const float*)d_in[0];
  const float* rb = (const float*)d_in[1];
  const float* Wq = (const float*)d_in[2];
  const float* bq = (const float*)d_in[3];
  const float* Wk = (const float*)d_in[4];
  const float* bk = (const float*)d_in[5];
  const float* Wv = (const float*)d_in[6];
  const float* bv = (const float*)d_in[7];
  const float* Wo = (const float*)d_in[8];
  const float* bo = (const float*)d_in[9];
  float* out = (float*)d_out;
  char* ws = (char*)d_ws;

  u16* xb   = (u16*)(ws);                 // 8 MB  [4096,1024] bf16 (reused as aout)
  u16* W1b  = (u16*)(ws + (8 << 20));     // 6 MB  [3072,1024] bf16 (Wq|Wk|Wv)
  u16* Wob  = (u16*)(ws + (14 << 20));    // 2 MB  [1024,1024] bf16
  u16* qb   = (u16*)(ws + (16 << 20));    // 8 MB  [B,H,L,HD]
  u16* kb2  = (u16*)(ws + (24 << 20));    // 8 MB  [B,H,L,HD]
  u16* vtb  = (u16*)(ws + (32 << 20));    // 8 MB  [B,H,HD,L] (written by QKV GEMM)
  u16* aout = xb;                         // alias: xb dead after QKV GEMM

  cvt_all<<<4096, 256, 0, stream>>>(x, Wq, Wk, Wv, Wo, xb, W1b, Wob);
  gemm_bt<0><<<dim3(24, 32), 256, 0, stream>>>(xb, W1b, qb, kb2, vtb, bq, bk, bv,
                                               nullptr, nullptr);
  attn_kernel<<<512, 512, 0, stream>>>(qb, kb2, vtb, rb, aout);
  gemm_bt<1><<<dim3(8, 32), 256, 0, stream>>>(aout, Wob, nullptr, nullptr, nullptr,
                                              nullptr, nullptr, nullptr, out, bo);
}

// Round 8
// 168.824 us; speedup vs baseline: 1.3388x; 1.0465x over previous
//
#include <hip/hip_runtime.h>

// MultiheadAttentionWithBias: B=2, L=2048, D=1024, H=16, HD=64
// cvt_all -> QKV GEMM (V^T fused epilogue) -> flash attn (8 waves/block,
// 128 q-rows, dbuf K/V, ONE barrier/iter, depth-2 bias prefetch, counted
// vmcnt, XCD swizzle) -> out GEMM.
// R8: attn schedule: single-barrier dbuf + 2-iter-deep bias pipeline.

typedef __attribute__((ext_vector_type(8))) short bf16x8;
typedef __attribute__((ext_vector_type(4))) float f32x4;
typedef __attribute__((ext_vector_type(8))) unsigned short u16x8;
using u16 = unsigned short;

#define MFMA16(a, b, c) __builtin_amdgcn_mfma_f32_16x16x32_bf16((a), (b), (c), 0, 0, 0)
#define LOG2E 1.44269504088896f
#define QSCALE (0.125f * 1.44269504088896f)

__device__ __forceinline__ u16 f2bf(float f) {
  union { float f; unsigned int u; } v; v.f = f;
  unsigned int r = v.u + 0x7FFFu + ((v.u >> 16) & 1u);
  return (u16)(r >> 16);
}

__device__ __forceinline__ unsigned cvt_pk_bf16(float lo, float hi) {
  unsigned r;
  asm volatile("v_cvt_pk_bf16_f32 %0, %1, %2" : "=v"(r) : "v"(lo), "v"(hi));
  return r;
}

__device__ __forceinline__ void g2lds16(const void* gsrc, void* ldst) {
  __builtin_amdgcn_global_load_lds(
      (const __attribute__((address_space(1))) unsigned int*)gsrc,
      (__attribute__((address_space(3))) unsigned int*)ldst, 16, 0, 0);
}

// ---------------- merged f32 -> bf16 convert (x, Wq, Wk, Wv, Wo) ----------------
__global__ __launch_bounds__(256) void cvt_all(
    const float* __restrict__ x, const float* __restrict__ wq,
    const float* __restrict__ wk, const float* __restrict__ wv,
    const float* __restrict__ wo, u16* __restrict__ xb,
    u16* __restrict__ w1b, u16* __restrict__ wob) {
  int bid = blockIdx.x, tid = threadIdx.x;
  const float* src; u16* dst; int i;
  if (bid < 2048)      { src = x;  dst = xb;            i = bid * 256 + tid; }
  else if (bid < 2560) { src = wq; dst = w1b;           i = (bid - 2048) * 256 + tid; }
  else if (bid < 3072) { src = wk; dst = w1b + (1<<20); i = (bid - 2560) * 256 + tid; }
  else if (bid < 3584) { src = wv; dst = w1b + (2<<20); i = (bid - 3072) * 256 + tid; }
  else                 { src = wo; dst = wob;           i = (bid - 3584) * 256 + tid; }
  const float4* s = (const float4*)src;
  float4 a = s[2 * i], b = s[2 * i + 1];
  u16x8 o;
  o[0] = f2bf(a.x); o[1] = f2bf(a.y); o[2] = f2bf(a.z); o[3] = f2bf(a.w);
  o[4] = f2bf(b.x); o[5] = f2bf(b.y); o[6] = f2bf(b.z); o[7] = f2bf(b.w);
  ((u16x8*)dst)[i] = o;
}

// ---------------- GEMM C = A * B^T ----------------
// MODE 0: scatter to q/k [B,H,L,HD] bf16 and V^T [B,H,HD,L] bf16 (+bias, q scaled).
// MODE 1: f32 out [M,1024] (+bias).
template <int MODE>
__global__ __launch_bounds__(256, 2) void gemm_bt(
    const u16* __restrict__ A, const u16* __restrict__ B,
    u16* __restrict__ qp, u16* __restrict__ kp, u16* __restrict__ vp,
    const float* __restrict__ b0, const float* __restrict__ b1,
    const float* __restrict__ b2, float* __restrict__ outp,
    const float* __restrict__ bo) {
  __shared__ __align__(16) u16 lA[128 * 64];
  __shared__ __align__(16) u16 lB[128 * 64];
  const int tid = threadIdx.x;
  const int lane = tid & 63, wid = tid >> 6;
  const int g = lane >> 4, cc = lane & 15;
  const int wr = wid >> 1, wc = wid & 1;
  const int m0 = blockIdx.y * 128, n0 = blockIdx.x * 128;
  f32x4 acc[4][4] = {};
  for (int kt = 0; kt < 16; ++kt) {
    const int kof = kt * 64;
#pragma unroll
    for (int i = 0; i < 4; ++i) {
      int cid = i * 256 + tid;
      int row = cid >> 3;
      int col = (cid & 7) * 8;
      g2lds16(A + (size_t)(m0 + row) * 1024 + kof + col, &lA[(i * 256 + wid * 64) * 8]);
      g2lds16(B + (size_t)(n0 + row) * 1024 + kof + col, &lB[(i * 256 + wid * 64) * 8]);
    }
    __syncthreads();
#pragma unroll
    for (int kc = 0; kc < 2; ++kc) {
      bf16x8 af[4], bfr[4];
#pragma unroll
      for (int mf = 0; mf < 4; ++mf)
        af[mf] = *(const bf16x8*)&lA[(wr * 64 + mf * 16 + cc) * 64 + kc * 32 + g * 8];
#pragma unroll
      for (int nf = 0; nf < 4; ++nf)
        bfr[nf] = *(const bf16x8*)&lB[(wc * 64 + nf * 16 + cc) * 64 + kc * 32 + g * 8];
#pragma unroll
      for (int mf = 0; mf < 4; ++mf)
#pragma unroll
        for (int nf = 0; nf < 4; ++nf)
          acc[mf][nf] = MFMA16(af[mf], bfr[nf], acc[mf][nf]);
    }
    __syncthreads();
  }
#pragma unroll
  for (int mf = 0; mf < 4; ++mf) {
#pragma unroll
    for (int nf = 0; nf < 4; ++nf) {
      int n = n0 + wc * 64 + nf * 16 + cc;
      if (MODE == 0) {
        int which = n >> 10;
        int nn = n & 1023;
        const float* bp = which == 0 ? b0 : (which == 1 ? b1 : b2);
        float bias = bp[nn];
        int h = nn >> 6, hd = nn & 63;
        int mb = m0 + wr * 64 + mf * 16 + g * 4;
        int bb = mb >> 11, ll0 = mb & 2047;
        if (which == 2) {
          // V^T fused: [B,H,HD,L]; 4 consecutive L per lane -> 8B store
          ushort4 pk4;
          pk4.x = f2bf(acc[mf][nf][0] + bias);
          pk4.y = f2bf(acc[mf][nf][1] + bias);
          pk4.z = f2bf(acc[mf][nf][2] + bias);
          pk4.w = f2bf(acc[mf][nf][3] + bias);
          *(ushort4*)&vp[(((size_t)(bb * 16 + h)) * 64 + hd) * 2048 + ll0] = pk4;
        } else {
          u16* dp = which == 0 ? qp : kp;
#pragma unroll
          for (int r = 0; r < 4; ++r) {
            float val = acc[mf][nf][r] + bias;
            if (which == 0) val *= QSCALE;
            dp[(((size_t)(bb * 16 + h)) * 2048 + ll0 + r) * 64 + hd] = f2bf(val);
          }
        }
      } else {
        float bias = bo[n];
#pragma unroll
        for (int r = 0; r < 4; ++r) {
          int m = m0 + wr * 64 + mf * 16 + g * 4 + r;
          outp[(size_t)m * 1024 + n] = acc[mf][nf][r] + bias;
        }
      }
    }
  }
}

// ---------------- Flash attention (single-barrier dbuf, depth-2 bias) ----------
// Block = 8 waves (512 thr), ONE (batch, head, 128-q-row strip). Per iter t:
//   stage K,V(t+1) -> buf^(P^1)   [2 g2lds, lands under full compute phase]
//   QK^T(buf P) + bias(t) [issued 2 iters ago -> no stall] + softmax
//   issue bias(t+2) [~1.7 iters of cover] ; P->LDS->PV(buf P)
//   vmcnt(4) [drains stage(t+1); bias(t+2) stays in flight] ; s_barrier
// ONE barrier per iteration. Outstanding-op audit at tail wait:
//   bias(t+1)[4, oldest] < stage(t+1)[2] < bias(t+2)[4, newest] -> vmcnt(4).
// XCD swizzle: xcd owns heads 2x,2x+1 -> K/V L2-resident (1MB/XCD).
__global__ __launch_bounds__(512, 4) void attn_kernel(
    const u16* __restrict__ qm, const u16* __restrict__ km,
    const u16* __restrict__ vtm, const float* __restrict__ bias,
    u16* __restrict__ aout) {
  __shared__ __align__(16) u16 lK[2][4096];   // dbuf 64x64 K tile: 16KB
  __shared__ __align__(16) u16 lV[2][4096];   // dbuf 64x64 V^T tile: 16KB
  __shared__ __align__(16) u16 plds[8192];    // 8 waves x 16x64 P tile: 16KB
  const int tid = threadIdx.x;
  const int lane = tid & 63, wid = tid >> 6;
  const int g = lane >> 4, cc = lane & 15;
  // XCD swizzle: 512 blocks, xcd = lin&7 owns heads 2*xcd, 2*xcd+1
  const int lin = blockIdx.x;
  const int xcd = lin & 7, j = lin >> 3;          // j in [0,64)
  const int h = xcd * 2 + (j >> 5);
  const int rem = j & 31;
  const int b = rem >> 4, qb = rem & 15;
  const int q0 = qb * 128;
  const size_t bh = (size_t)b * 16 + h;
  const u16* kg = km + bh * 2048 * 64;
  const u16* vg = vtm + bh * 64 * 2048;
  const u16* qbase = qm + (bh * 2048 + q0 + wid * 16) * 64;
  const float* brow = bias + ((size_t)h * 2048 + q0 + wid * 16 + cc) * 2048;
  u16* plw = plds + wid * 1024;

  bf16x8 qf0 = *(const bf16x8*)&qbase[(size_t)cc * 64 + g * 8];
  bf16x8 qf1 = *(const bf16x8*)&qbase[(size_t)cc * 64 + 32 + g * 8];
  f32x4 o[4] = {};
  float mrow = -3.0e38f, lrow = 0.f;

  // stage one 64x64 tile with 512 threads (1 g2lds each), pre-swizzled source
#define STAGE_TILE(gbase, rs, ldst)                                            \
  {                                                                            \
    int row = tid >> 3, pcol = tid & 7;                                        \
    int lcol = pcol ^ (row & 7);                                               \
    g2lds16((gbase) + (size_t)row * (rs) + lcol * 8, (ldst) + tid * 8);        \
  }

  float4 bA[4], bB[4];
  // prologue: stage K(0),V(0) -> buf0 (oldest 2), bias(0)->bA, bias(1)->bB
  STAGE_TILE(kg, 64, (u16*)lK[0])
  STAGE_TILE(vg, 2048, (u16*)lV[0])
  __builtin_amdgcn_sched_barrier(0);
#pragma unroll
  for (int kb = 0; kb < 4; ++kb) {
    bA[kb] = *(const float4*)(brow + kb * 16 + g * 4);
    bB[kb] = *(const float4*)(brow + 64 + kb * 16 + g * 4);
  }
  __builtin_amdgcn_sched_barrier(0);
  asm volatile("s_waitcnt vmcnt(8)" ::: "memory");  // K/V(0) landed, bias flying
  __builtin_amdgcn_sched_barrier(0);
  __builtin_amdgcn_s_barrier();
  __builtin_amdgcn_sched_barrier(0);

  // DOSTAGE: stage t+1 exists (t<31). DOBIAS: bias t+2 exists (t<30).
#define ATTN_STEP(kt_, BC, DOSTAGE, DOBIAS)                                    \
  {                                                                            \
    const int k0 = (kt_) * 64;                                                 \
    const int P = (kt_) & 1;                                                   \
    if (DOSTAGE) {                                                             \
      STAGE_TILE(kg + (size_t)(k0 + 64) * 64, 64, (u16*)lK[P ^ 1])             \
      STAGE_TILE(vg + (k0 + 64), 2048, (u16*)lV[P ^ 1])                        \
    }                                                                          \
    __builtin_amdgcn_sched_barrier(0);                                         \
    /* S^T = K Q^T : lane(g,cc) -> S[q=cc][k=kb*16+g*4+r] */                   \
    f32x4 s[4];                                                                \
    _Pragma("unroll") for (int kb = 0; kb < 4; ++kb) {                         \
      int row = kb * 16 + cc;                                                  \
      bf16x8 ka = *(const bf16x8*)&lK[P][row * 64 + ((0 + g) ^ (cc & 7)) * 8]; \
      bf16x8 kbf = *(const bf16x8*)&lK[P][row * 64 + ((4 + g) ^ (cc & 7)) * 8];\
      f32x4 z = {};                                                            \
      z = MFMA16(ka, qf0, z);                                                  \
      z = MFMA16(kbf, qf1, z);                                                 \
      s[kb] = z;                                                               \
    }                                                                          \
    _Pragma("unroll") for (int kb = 0; kb < 4; ++kb) {                         \
      s[kb][0] = fmaf(BC[kb].x, LOG2E, s[kb][0]);                              \
      s[kb][1] = fmaf(BC[kb].y, LOG2E, s[kb][1]);                              \
      s[kb][2] = fmaf(BC[kb].z, LOG2E, s[kb][2]);                              \
      s[kb][3] = fmaf(BC[kb].w, LOG2E, s[kb][3]);                              \
    }                                                                          \
    /* online softmax, per-iter rescale (R3-proven) */                         \
    float rmax = s[0][0];                                                      \
    _Pragma("unroll") for (int kb = 0; kb < 4; ++kb)                           \
        _Pragma("unroll") for (int r = 0; r < 4; ++r)                          \
            rmax = fmaxf(rmax, s[kb][r]);                                      \
    rmax = fmaxf(rmax, __shfl_xor(rmax, 16, 64));                              \
    rmax = fmaxf(rmax, __shfl_xor(rmax, 32, 64));                              \
    float mnew = fmaxf(mrow, rmax);                                            \
    float sc = __builtin_amdgcn_exp2f(mrow - mnew);                            \
    mrow = mnew;                                                               \
    float psum = 0.f;                                                          \
    _Pragma("unroll") for (int kb = 0; kb < 4; ++kb)                           \
        _Pragma("unroll") for (int r = 0; r < 4; ++r) {                        \
      s[kb][r] = __builtin_amdgcn_exp2f(s[kb][r] - mrow);                      \
      psum += s[kb][r];                                                        \
    }                                                                          \
    psum += __shfl_xor(psum, 16, 64);                                          \
    psum += __shfl_xor(psum, 32, 64);                                          \
    lrow = lrow * sc + psum;                                                   \
    float scb[4];                                                              \
    _Pragma("unroll") for (int r = 0; r < 4; ++r)                              \
        scb[r] = __shfl(sc, (lane & 48) | (((lane >> 4) & 3) * 4 + r), 64);    \
    _Pragma("unroll") for (int td = 0; td < 4; ++td)                           \
        _Pragma("unroll") for (int r = 0; r < 4; ++r) o[td][r] *= scb[r];      \
    /* issue bias(t+2) into just-consumed regs (~1.7 iters of cover) */        \
    if (DOBIAS) {                                                              \
      _Pragma("unroll") for (int kb = 0; kb < 4; ++kb)                         \
          BC[kb] = *(const float4*)(brow + k0 + 128 + kb * 16 + g * 4);        \
    }                                                                          \
    __builtin_amdgcn_sched_barrier(0);                                         \
    /* P -> wave-private swizzled LDS -> A-frags */                            \
    _Pragma("unroll") for (int kb = 0; kb < 4; ++kb) {                         \
      unsigned lo = cvt_pk_bf16(s[kb][0], s[kb][1]);                           \
      unsigned hi = cvt_pk_bf16(s[kb][2], s[kb][3]);                           \
      int ch = (kb * 4 + g) ^ ((cc & 7) << 1);                                 \
      ((uint2*)plw)[cc * 16 + ch] = make_uint2(lo, hi);                        \
    }                                                                          \
    bf16x8 pf0 = *(const bf16x8*)&plw[cc * 64 + (((2 * g) ^ ((cc & 7) << 1)) * 4)]; \
    bf16x8 pf1 = *(const bf16x8*)&plw[cc * 64 + (((8 + 2 * g) ^ ((cc & 7) << 1)) * 4)]; \
    _Pragma("unroll") for (int td = 0; td < 4; ++td) {                         \
      int row = td * 16 + cc;                                                  \
      bf16x8 va = *(const bf16x8*)&lV[P][row * 64 + ((0 + g) ^ (cc & 7)) * 8]; \
      bf16x8 vb = *(const bf16x8*)&lV[P][row * 64 + ((4 + g) ^ (cc & 7)) * 8]; \
      o[td] = MFMA16(pf0, va, o[td]);                                          \
      o[td] = MFMA16(pf1, vb, o[td]);                                          \
    }                                                                          \
    /* drain stage(t+1) [bias(t+2) stays in flight], then ONE barrier */       \
    __builtin_amdgcn_sched_barrier(0);                                         \
    if (DOSTAGE && DOBIAS) { asm volatile("s_waitcnt vmcnt(4)" ::: "memory"); }\
    else                   { asm volatile("s_waitcnt vmcnt(0)" ::: "memory"); }\
    __builtin_amdgcn_sched_barrier(0);                                         \
    if (DOSTAGE) { __builtin_amdgcn_s_barrier(); }                             \
    __builtin_amdgcn_sched_barrier(0);                                         \
  }

  for (int kt = 0; kt < 30; kt += 2) {
    ATTN_STEP(kt, bA, 1, 1)
    ATTN_STEP(kt + 1, bB, 1, 1)
  }
  ATTN_STEP(30, bA, 1, 0)
  ATTN_STEP(31, bB, 0, 0)
#undef ATTN_STEP
#undef STAGE_TILE

  // normalize + write [B, L, 1024] bf16
  float linv = 1.0f / lrow;
  float lb[4];
#pragma unroll
  for (int r = 0; r < 4; ++r)
    lb[r] = __shfl(linv, (lane & 48) | (((lane >> 4) & 3) * 4 + r), 64);
#pragma unroll
  for (int td = 0; td < 4; ++td)
#pragma unroll
    for (int r = 0; r < 4; ++r) {
      float val = o[td][r] * lb[r];
      int qg = q0 + wid * 16 + g * 4 + r;
      aout[((size_t)b * 2048 + qg) * 1024 + h * 64 + td * 16 + cc] = f2bf(val);
    }
}

extern "C" void kernel_launch(void* const* d_in, const int* in_sizes, int n_in,
                              void* d_out, int out_size, void* d_ws, size_t ws_size,
                              hipStream_t stream) {
  const float* x  = (const float*)d_in[0];
  const float* rb = (const float*)d_in[1];
  const float* Wq = (const float*)d_in[2];
  const float* bq = (const float*)d_in[3];
  const float* Wk = (const float*)d_in[4];
  const float* bk = (const float*)d_in[5];
  const float* Wv = (const float*)d_in[6];
  const float* bv = (const float*)d_in[7];
  const float* Wo = (const float*)d_in[8];
  const float* bo = (const float*)d_in[9];
  float* out = (float*)d_out;
  char* ws = (char*)d_ws;

  u16* xb   = (u16*)(ws);                 // 8 MB  [4096,1024] bf16 (reused as aout)
  u16* W1b  = (u16*)(ws + (8 << 20));     // 6 MB  [3072,1024] bf16 (Wq|Wk|Wv)
  u16* Wob  = (u16*)(ws + (14 << 20));    // 2 MB  [1024,1024] bf16
  u16* qb   = (u16*)(ws + (16 << 20));    // 8 MB  [B,H,L,HD]
  u16* kb2  = (u16*)(ws + (24 << 20));    // 8 MB  [B,H,L,HD]
  u16* vtb  = (u16*)(ws + (32 << 20));    // 8 MB  [B,H,HD,L] (written by QKV GEMM)
  u16* aout = xb;                         // alias: xb dead after QKV GEMM

  cvt_all<<<4096, 256, 0, stream>>>(x, Wq, Wk, Wv, Wo, xb, W1b, Wob);
  gemm_bt<0><<<dim3(24, 32), 256, 0, stream>>>(xb, W1b, qb, kb2, vtb, bq, bk, bv,
                                               nullptr, nullptr);
  attn_kernel<<<512, 512, 0, stream>>>(qb, kb2, vtb, rb, aout);
  gemm_bt<1><<<dim3(8, 32), 256, 0, stream>>>(aout, Wob, nullptr, nullptr, nullptr,
                                              nullptr, nullptr, nullptr, out, bo);
}